// Round 7
// baseline (835.740 us; speedup 1.0000x reference)
//
#include <hip/hip_runtime.h>
#include <hip/hip_bf16.h>
#include <math.h>

#define B_ 4
#define T_ 4096
#define D_ 2048
#define H_ 128
#define M_ (B_*T_)   // 16384 rows

// Measurement round: real attn (v4 structure) at REP=2 for rocprof
// visibility; three ablation clones at REP=6 writing to dead scratch.
#define REP_ATTN 2
#define REP_AB   6

typedef __bf16 bf16;
typedef __attribute__((ext_vector_type(8))) __bf16 bf16x8;
typedef __attribute__((ext_vector_type(4))) float f32x4;
typedef __attribute__((ext_vector_type(16))) float f32x16;

#define MFMA16(a,b,c) __builtin_amdgcn_mfma_f32_16x16x32_bf16(a,b,c,0,0,0)
#define MFMA32(a,b,c) __builtin_amdgcn_mfma_f32_32x32x16_bf16(a,b,c,0,0,0)

typedef __attribute__((address_space(3))) unsigned int lds_u32_t;
typedef const __attribute__((address_space(1))) unsigned int glb_u32_t;

__device__ __forceinline__ void cp16(void* lds, const void* g) {
    __builtin_amdgcn_global_load_lds((glb_u32_t*)g, (lds_u32_t*)lds, 16, 0, 0);
}

// ws layout (bytes)
#define QOFF   0u
#define KOFF   (4u<<20)
#define VTOFF  (8u<<20)
#define WTOFF  (12u<<20)            // 3 * 128 * 2048 bf16 = 1.5 MiB
#define OPOFF  (14u<<20)            // ks=1..3 partial O, fp32, 3 x 8 MiB
#define LPOFF  (OPOFF + 25165824u)  // l partials [4][16384] fp32
#define SCROFF (64u<<20)            // ablation scratch (never read)

// ---------------------------------------------------------------------------
// W convert+transpose: W[2048][128] fp32 -> Wt[mat][128][2048] bf16.
// ---------------------------------------------------------------------------
__global__ __launch_bounds__(256) void cvtw_kernel(
    const float* __restrict__ Wq, const float* __restrict__ Wk,
    const float* __restrict__ Wv, bf16* __restrict__ Wtb)
{
    __shared__ __align__(16) bf16 U[128 * 72];   // [n][k], stride 72
    const int tid = threadIdx.x;
    const int m  = blockIdx.x >> 5;              // 0..2
    const int kt = blockIdx.x & 31;              // 0..31
    const int k0 = kt * 64;
    const float* W = (m == 0) ? Wq : ((m == 1) ? Wk : Wv);
    const float sc = (m == 0) ? 0.12753102105128444f : 1.0f;  // log2e/sqrt(128)

    #pragma unroll
    for (int u = 0; u < 8; u++) {
        int id = tid + u * 256;
        int kr = id >> 5, c4 = id & 31;
        float4 v = *(const float4*)(W + (size_t)(k0 + kr) * H_ + c4 * 4);
        U[(c4*4 + 0) * 72 + kr] = (bf16)(v.x * sc);
        U[(c4*4 + 1) * 72 + kr] = (bf16)(v.y * sc);
        U[(c4*4 + 2) * 72 + kr] = (bf16)(v.z * sc);
        U[(c4*4 + 3) * 72 + kr] = (bf16)(v.w * sc);
    }
    __syncthreads();
    #pragma unroll
    for (int u = 0; u < 4; u++) {
        int id = tid + u * 256;
        int n = id >> 3, kc = id & 7;
        bf16x8 v = *(const bf16x8*)((const char*)U + n * 144 + kc * 16);
        *(bf16x8*)((char*)Wtb + (size_t)m * 524288 + (size_t)n * 4096
                   + k0 * 2 + kc * 16) = v;
    }
}

// ---------------------------------------------------------------------------
// Fused QKV projection (unchanged).
// ---------------------------------------------------------------------------
__global__ __launch_bounds__(512, 2) void proj_kernel(
    const float* __restrict__ X, const bf16* __restrict__ Wtb,
    bf16* __restrict__ Qb, bf16* __restrict__ Kb, bf16* __restrict__ Vtb)
{
    __shared__ __align__(16) char smem[114688];

    const int tid = threadIdx.x;
    const int w = tid >> 6, lane = tid & 63;
    const int c31 = lane & 31, kh = lane >> 5;
    const int mh = w >> 2;
    const int ng = w & 3;
    const int m0 = blockIdx.x * 64;

    f32x16 acc[3];
    #pragma unroll
    for (int t = 0; t < 3; t++)
        #pragma unroll
        for (int r = 0; r < 16; r++) acc[t][r] = 0.f;

    #pragma unroll
    for (int u = 0; u < 6; u++) {
        int s = tid + u * 512;
        int n = s >> 3, ccs = s & 7;
        int kc = ccs ^ (n & 7);
        int mat = n >> 7, ncol = n & 127;
        cp16(smem + 16384 + s * 16,
             (const char*)Wtb + (size_t)mat * 524288 + (size_t)ncol * 4096 + kc * 16);
    }
    {
        int r = tid >> 3, cc = tid & 7;
        const float* src = X + (size_t)(m0 + r) * D_ + cc * 8;
        float4 v0 = *(const float4*)src;
        float4 v1 = *(const float4*)(src + 4);
        union { bf16 h[8]; uint4 u4; } pk;
        pk.h[0]=(bf16)v0.x; pk.h[1]=(bf16)v0.y; pk.h[2]=(bf16)v0.z; pk.h[3]=(bf16)v0.w;
        pk.h[4]=(bf16)v1.x; pk.h[5]=(bf16)v1.y; pk.h[6]=(bf16)v1.z; pk.h[7]=(bf16)v1.w;
        *(uint4*)(smem + (r * 8 + (cc ^ (r & 7))) * 16) = pk.u4;
    }
    __syncthreads();

    for (int it = 0; it < 32; it++) {
        const int cur = it & 1;
        char* xcur = smem + cur * 8192;
        char* wcur = smem + 16384 + cur * 49152;
        float4 xv0, xv1;
        if (it < 31) {
            const int k1 = (it + 1) * 64;
            char* wnxt = smem + 16384 + (cur ^ 1) * 49152;
            #pragma unroll
            for (int u = 0; u < 6; u++) {
                int s = tid + u * 512;
                int n = s >> 3, ccs = s & 7;
                int kc = ccs ^ (n & 7);
                int mat = n >> 7, ncol = n & 127;
                cp16(wnxt + s * 16,
                     (const char*)Wtb + (size_t)mat * 524288 + (size_t)ncol * 4096
                     + k1 * 2 + kc * 16);
            }
            int r = tid >> 3, cc = tid & 7;
            const float* src = X + (size_t)(m0 + r) * D_ + k1 + cc * 8;
            xv0 = *(const float4*)src;
            xv1 = *(const float4*)(src + 4);
        }
        #pragma unroll
        for (int s = 0; s < 4; s++) {
            int c = s * 2 + kh;
            int rr = mh * 32 + c31;
            bf16x8 af = *(const bf16x8*)(xcur + (rr * 8 + (c ^ (rr & 7))) * 16);
            #pragma unroll
            for (int t = 0; t < 3; t++) {
                int n = ng * 96 + t * 32 + c31;
                bf16x8 bfr = *(const bf16x8*)(wcur + (n * 8 + (c ^ (n & 7))) * 16);
                acc[t] = MFMA32(af, bfr, acc[t]);
            }
        }
        if (it < 31) {
            char* xnxt = smem + (cur ^ 1) * 8192;
            int r = tid >> 3, cc = tid & 7;
            union { bf16 h[8]; uint4 u4; } pk;
            pk.h[0]=(bf16)xv0.x; pk.h[1]=(bf16)xv0.y; pk.h[2]=(bf16)xv0.z; pk.h[3]=(bf16)xv0.w;
            pk.h[4]=(bf16)xv1.x; pk.h[5]=(bf16)xv1.y; pk.h[6]=(bf16)xv1.z; pk.h[7]=(bf16)xv1.w;
            *(uint4*)(xnxt + (r * 8 + (cc ^ (r & 7))) * 16) = pk.u4;
        }
        __syncthreads();
    }

    #pragma unroll
    for (int t = 0; t < 3; t++) {
        int nb = ng * 96 + t * 32;
        if ((nb >> 7) == 2) {
            int ncol = (nb & 127) + c31;
            #pragma unroll
            for (int g = 0; g < 4; g++) {
                int m = m0 + mh * 32 + g * 8 + kh * 4;
                union { bf16 h[4]; uint2 u2; } pk;
                #pragma unroll
                for (int e = 0; e < 4; e++) pk.h[e] = (bf16)acc[t][g*4 + e];
                *(uint2*)((char*)Vtb + (size_t)ncol * 32768 + (size_t)m * 2) = pk.u2;
            }
        }
    }
    bf16* U = (bf16*)smem;
    #pragma unroll
    for (int mat = 0; mat < 2; mat++) {
        __syncthreads();
        #pragma unroll
        for (int t = 0; t < 3; t++) {
            int nb = ng * 96 + t * 32;
            if ((nb >> 7) == mat) {
                int lcol = (nb & 127) + c31;
                #pragma unroll
                for (int r = 0; r < 16; r++) {
                    int row = mh * 32 + (r & 3) + 8 * (r >> 2) + 4 * kh;
                    U[row * 136 + lcol] = (bf16)acc[t][r];
                }
            }
        }
        __syncthreads();
        bf16* og = (mat == 0) ? Qb : Kb;
        #pragma unroll
        for (int u = 0; u < 2; u++) {
            int id = tid + u * 512;
            int rr = id >> 4, cc = id & 15;
            bf16x8 v = *(const bf16x8*)((const char*)U + rr * 272 + cc * 16);
            *(bf16x8*)((char*)og + (size_t)(m0 + rr) * 256 + cc * 16) = v;
        }
    }
}

// ---------------------------------------------------------------------------
// Flash attention v4 (reverted best-known): 4 waves x 32 q-rows; KVBLK=32;
// K+V double-buffered in LDS; wave-private P (pitch 80B).
// ---------------------------------------------------------------------------
__global__ __launch_bounds__(256, 3) void attn_kernel(
    const bf16* __restrict__ Qb, const bf16* __restrict__ Kb,
    const bf16* __restrict__ Vtb,
    float* __restrict__ Out0, float* __restrict__ Opart,
    float* __restrict__ lpart)
{
    __shared__ __align__(16) char smem[43008];
    // Ks: 0 / 8192 | Vs: 16384 / 24576 | P: 32768 (4 waves x 32 rows x 80B)

    const int tid = threadIdx.x;
    const int w = tid >> 6, lane = tid & 63;
    const int c15 = lane & 15, quad = (lane >> 4) & 3;

    const int bx = blockIdx.x;
    const int ks = bx & 3;
    const int qt = bx >> 2;             // 0..127
    const int b = qt >> 5;
    const int row0 = b*T_ + (qt & 31)*128;
    const int kvrow = b*T_ + ks*1024;

    bf16x8 qf[2][4];
    #pragma unroll
    for (int mg = 0; mg < 2; mg++) {
        const char* qrow = (const char*)Qb
            + (size_t)(row0 + w*32 + mg*16 + c15) * 256 + quad*16;
        #pragma unroll
        for (int kk = 0; kk < 4; kk++)
            qf[mg][kk] = *(const bf16x8*)(qrow + kk*64);
    }

    const int fv = (quad ^ ((c15 >> 1) & 3)) & 3;

    f32x4 o[2][8];
    float lsum[2];

    for (int rep = 0; rep < REP_ATTN; rep++) {
    #pragma unroll
    for (int mg = 0; mg < 2; mg++)
        #pragma unroll
        for (int ng = 0; ng < 8; ng++)
            #pragma unroll
            for (int r = 0; r < 4; r++) o[mg][ng][r] = 0.f;
    lsum[0] = 0.f; lsum[1] = 0.f;

    #pragma unroll
    for (int u = 0; u < 2; u++) {
        int s = tid + u*256;
        int r = s >> 4, csw = s & 15;
        int cg = (csw & 8) | ((csw ^ r) & 7);
        cp16(smem + s*16, (const char*)Kb + (size_t)(kvrow + r)*256 + cg*16);
    }
    #pragma unroll
    for (int u = 0; u < 2; u++) {
        int s = tid + u*256;
        int n = s >> 2, f = s & 3;
        int cv = (f ^ ((n >> 1) & 3)) & 3;
        cp16(smem + 16384 + s*16,
             (const char*)Vtb + (size_t)n*32768 + (size_t)(kvrow + cv*8)*2);
    }
    __syncthreads();

    for (int it = 0; it < 32; it++) {
        const int cur = it & 1;
        char* ksb = smem + cur*8192;
        char* vsb = smem + 16384 + cur*8192;
        if (it < 31) {
            const int knx = kvrow + (it + 1)*32;
            #pragma unroll
            for (int u = 0; u < 2; u++) {
                int s = tid + u*256;
                int r = s >> 4, csw = s & 15;
                int cg = (csw & 8) | ((csw ^ r) & 7);
                cp16(smem + (cur^1)*8192 + s*16,
                     (const char*)Kb + (size_t)(knx + r)*256 + cg*16);
            }
            #pragma unroll
            for (int u = 0; u < 2; u++) {
                int s = tid + u*256;
                int n = s >> 2, f = s & 3;
                int cv = (f ^ ((n >> 1) & 3)) & 3;
                cp16(smem + 16384 + (cur^1)*8192 + s*16,
                     (const char*)Vtb + (size_t)n*32768 + (size_t)(knx + cv*8)*2);
            }
        }

        char* Pw = smem + 32768 + w*2560;
        #pragma unroll
        for (int kq = 0; kq < 2; kq++) {
            const int key = kq*16 + c15;
            bf16x8 kf[4];
            #pragma unroll
            for (int kk = 0; kk < 4; kk++) {
                int ck = kk*4 + quad;
                kf[kk] = *(const bf16x8*)(ksb
                    + (key*16 + ((ck & 8) | ((ck ^ key) & 7)))*16);
            }
            #pragma unroll
            for (int mg = 0; mg < 2; mg++) {
                f32x4 sc = (f32x4){0.f,0.f,0.f,0.f};
                __builtin_amdgcn_s_setprio(1);
                #pragma unroll
                for (int kk = 0; kk < 4; kk++)
                    sc = MFMA16(kf[kk], qf[mg][kk], sc);
                __builtin_amdgcn_s_setprio(0);
                union { bf16 h[4]; uint2 u2; } pk;
                #pragma unroll
                for (int r = 0; r < 4; r++) {
                    float p = exp2f(sc[r]);
                    lsum[mg] += p;
                    pk.h[r] = (bf16)p;
                }
                *(uint2*)(Pw + (mg*16 + c15)*80 + kq*32 + quad*8) = pk.u2;
            }
        }

        bf16x8 pf0 = *(const bf16x8*)(Pw + c15*80 + quad*16);
        bf16x8 pf1 = *(const bf16x8*)(Pw + (16 + c15)*80 + quad*16);
        __builtin_amdgcn_s_setprio(1);
        #pragma unroll
        for (int ng = 0; ng < 8; ng++) {
            int n = ng*16 + c15;
            bf16x8 vf = *(const bf16x8*)(vsb + (n*8 + ((fv*2) & 7) + 0)*0
                                          + n*64 + fv*16);
            o[0][ng] = MFMA16(pf0, vf, o[0][ng]);
            o[1][ng] = MFMA16(pf1, vf, o[1][ng]);
        }
        __builtin_amdgcn_s_setprio(0);

        __syncthreads();
    }
    }  // rep

    __syncthreads();
    float* lred = (float*)(smem + 32768);
    #pragma unroll
    for (int mg = 0; mg < 2; mg++) {
        float v = lsum[mg];
        v += __shfl_xor(v, 16);
        v += __shfl_xor(v, 32);
        if (lane < 16) lred[w*32 + mg*16 + c15] = v;
    }
    __syncthreads();
    if (tid < 128)
        lpart[ks*M_ + row0 + tid] = lred[tid];

    float* Od = (ks == 0) ? Out0 : (Opart + (size_t)(ks - 1) * M_ * H_);
    #pragma unroll
    for (int mg = 0; mg < 2; mg++)
        #pragma unroll
        for (int ng = 0; ng < 8; ng++)
            #pragma unroll
            for (int r = 0; r < 4; r++)
                Od[(size_t)(row0 + w*32 + mg*16 + quad*4 + r)*H_ + ng*16 + c15]
                    = o[mg][ng][r];
}

// ---------------------------------------------------------------------------
// Ablation clones of v4. Output goes to dead scratch (never read).
// VAR 0 = NOSTAGE (stage once, no per-iter cp16/barrier; asm clobber per it)
// VAR 1 = NOPV    (full staging+barrier+S+exp+P-write; no P-read/PV)
// VAR 2 = SKEL    (staging + barrier only)
// ---------------------------------------------------------------------------
template<int VAR>
__global__ __launch_bounds__(256, 3) void attn_ab(
    const bf16* __restrict__ Qb, const bf16* __restrict__ Kb,
    const bf16* __restrict__ Vtb, float* __restrict__ scr)
{
    __shared__ __align__(16) char smem[43008];

    const int tid = threadIdx.x;
    const int w = tid >> 6, lane = tid & 63;
    const int c15 = lane & 15, quad = (lane >> 4) & 3;

    const int bx = blockIdx.x;
    const int ks = bx & 3;
    const int qt = bx >> 2;
    const int b = qt >> 5;
    const int row0 = b*T_ + (qt & 31)*128;
    const int kvrow = b*T_ + ks*1024;

    bf16x8 qf[2][4];
    #pragma unroll
    for (int mg = 0; mg < 2; mg++) {
        const char* qrow = (const char*)Qb
            + (size_t)(row0 + w*32 + mg*16 + c15) * 256 + quad*16;
        #pragma unroll
        for (int kk = 0; kk < 4; kk++)
            qf[mg][kk] = *(const bf16x8*)(qrow + kk*64);
    }

    f32x4 o[2][8];
    float lsum[2];
    #pragma unroll
    for (int mg = 0; mg < 2; mg++)
        #pragma unroll
        for (int ng = 0; ng < 8; ng++)
            #pragma unroll
            for (int r = 0; r < 4; r++) o[mg][ng][r] = 0.f;
    lsum[0] = 0.f; lsum[1] = 0.f;

    if (VAR == 0) {
        // stage both buffers once
        #pragma unroll
        for (int cur = 0; cur < 2; cur++) {
            const int kr = kvrow + cur*32;
            #pragma unroll
            for (int u = 0; u < 2; u++) {
                int s = tid + u*256;
                int r = s >> 4, csw = s & 15;
                int cg = (csw & 8) | ((csw ^ r) & 7);
                cp16(smem + cur*8192 + s*16,
                     (const char*)Kb + (size_t)(kr + r)*256 + cg*16);
            }
            #pragma unroll
            for (int u = 0; u < 2; u++) {
                int s = tid + u*256;
                int n = s >> 2, f = s & 3;
                int cv = (f ^ ((n >> 1) & 3)) & 3;
                cp16(smem + 16384 + cur*8192 + s*16,
                     (const char*)Vtb + (size_t)n*32768 + (size_t)(kr + cv*8)*2);
            }
        }
        __syncthreads();
    } else {
        #pragma unroll
        for (int u = 0; u < 2; u++) {
            int s = tid + u*256;
            int r = s >> 4, csw = s & 15;
            int cg = (csw & 8) | ((csw ^ r) & 7);
            cp16(smem + s*16, (const char*)Kb + (size_t)(kvrow + r)*256 + cg*16);
        }
        #pragma unroll
        for (int u = 0; u < 2; u++) {
            int s = tid + u*256;
            int n = s >> 2, f = s & 3;
            int cv = (f ^ ((n >> 1) & 3)) & 3;
            cp16(smem + 16384 + s*16,
                 (const char*)Vtb + (size_t)n*32768 + (size_t)(kvrow + cv*8)*2);
        }
        __syncthreads();
    }

    const int fv = (quad ^ ((c15 >> 1) & 3)) & 3;

    for (int rep = 0; rep < REP_AB; rep++) {
    for (int it = 0; it < 32; it++) {
        const int cur = it & 1;
        char* ksb = smem + cur*8192;
        char* vsb = smem + 16384 + cur*8192;

        if (VAR != 0 && it < 31) {
            const int knx = kvrow + (it + 1)*32;
            #pragma unroll
            for (int u = 0; u < 2; u++) {
                int s = tid + u*256;
                int r = s >> 4, csw = s & 15;
                int cg = (csw & 8) | ((csw ^ r) & 7);
                cp16(smem + (cur^1)*8192 + s*16,
                     (const char*)Kb + (size_t)(knx + r)*256 + cg*16);
            }
            #pragma unroll
            for (int u = 0; u < 2; u++) {
                int s = tid + u*256;
                int n = s >> 2, f = s & 3;
                int cv = (f ^ ((n >> 1) & 3)) & 3;
                cp16(smem + 16384 + (cur^1)*8192 + s*16,
                     (const char*)Vtb + (size_t)n*32768 + (size_t)(knx + cv*8)*2);
            }
        }

        if (VAR != 2) {
            // S phase
            char* Pw = smem + 32768 + w*2560;
            #pragma unroll
            for (int kq = 0; kq < 2; kq++) {
                const int key = kq*16 + c15;
                bf16x8 kf[4];
                #pragma unroll
                for (int kk = 0; kk < 4; kk++) {
                    int ck = kk*4 + quad;
                    kf[kk] = *(const bf16x8*)(ksb
                        + (key*16 + ((ck & 8) | ((ck ^ key) & 7)))*16);
                }
                #pragma unroll
                for (int mg = 0; mg < 2; mg++) {
                    f32x4 sc = (f32x4){0.f,0.f,0.f,0.f};
                    __builtin_amdgcn_s_setprio(1);
                    #pragma unroll
                    for (int kk = 0; kk < 4; kk++)
                        sc = MFMA16(kf[kk], qf[mg][kk], sc);
                    __builtin_amdgcn_s_setprio(0);
                    union { bf16 h[4]; uint2 u2; } pk;
                    #pragma unroll
                    for (int r = 0; r < 4; r++) {
                        float p = exp2f(sc[r]);
                        lsum[mg] += p;
                        pk.h[r] = (bf16)p;
                    }
                    *(uint2*)(Pw + (mg*16 + c15)*80 + kq*32 + quad*8) = pk.u2;
                }
            }
            if (VAR == 0) {
                // full compute: PV as well
                bf16x8 pf0 = *(const bf16x8*)(Pw + c15*80 + quad*16);
                bf16x8 pf1 = *(const bf16x8*)(Pw + (16 + c15)*80 + quad*16);
                __builtin_amdgcn_s_setprio(1);
                #pragma unroll
                for (int ng = 0; ng < 8; ng++) {
                    int n = ng*16 + c15;
                    bf16x8 vf = *(const bf16x8*)(vsb + n*64 + fv*16);
                    o[0][ng] = MFMA16(pf0, vf, o[0][ng]);
                    o[1][ng] = MFMA16(pf1, vf, o[1][ng]);
                }
                __builtin_amdgcn_s_setprio(0);
            }
        }

        if (VAR == 0) {
            asm volatile("" ::: "memory");   // block cross-iter CSE/hoist
        } else {
            __syncthreads();
        }
    }
    }  // rep

    // keep-alive epilogue to dead scratch
    float acc = lsum[0] + lsum[1];
    #pragma unroll
    for (int mg = 0; mg < 2; mg++)
        #pragma unroll
        for (int ng = 0; ng < 8; ng++)
            #pragma unroll
            for (int r = 0; r < 4; r++) acc += o[mg][ng][r];
    if (VAR == 2) acc += *(volatile float*)(smem + (tid & 127)*16);
    scr[(size_t)bx*256 + tid] = acc;
}

// ---------------------------------------------------------------------------
// Merge: out = (O0 + O1 + O2 + O3) / (l0 + l1 + l2 + l3)
// ---------------------------------------------------------------------------
__global__ __launch_bounds__(256) void merge_kernel(
    float* __restrict__ Out, const float* __restrict__ Opart,
    const float* __restrict__ lp)
{
    int id = blockIdx.x * 256 + threadIdx.x;   // 524288 float4 groups
    int row = id >> 5;
    float inv = 1.0f / (lp[row] + lp[M_ + row] + lp[2*M_ + row] + lp[3*M_ + row]);
    float4 a = *(const float4*)(Out + (size_t)id*4);
    float4 b1 = *(const float4*)(Opart + (size_t)id*4);
    float4 b2 = *(const float4*)(Opart + (size_t)M_*H_ + (size_t)id*4);
    float4 b3 = *(const float4*)(Opart + (size_t)2*M_*H_ + (size_t)id*4);
    float4 rr;
    rr.x = (a.x + b1.x + b2.x + b3.x) * inv;
    rr.y = (a.y + b1.y + b2.y + b3.y) * inv;
    rr.z = (a.z + b1.z + b2.z + b3.z) * inv;
    rr.w = (a.w + b1.w + b2.w + b3.w) * inv;
    *(float4*)(Out + (size_t)id*4) = rr;
}

extern "C" void kernel_launch(void* const* d_in, const int* in_sizes, int n_in,
                              void* d_out, int out_size, void* d_ws, size_t ws_size,
                              hipStream_t stream) {
    const float* x  = (const float*)d_in[0];
    const float* Wq = (const float*)d_in[1];
    const float* Wk = (const float*)d_in[2];
    const float* Wv = (const float*)d_in[3];
    float* outp = (float*)d_out;
    char* ws = (char*)d_ws;

    bf16* Qb  = (bf16*)(ws + QOFF);
    bf16* Kb  = (bf16*)(ws + KOFF);
    bf16* Vtb = (bf16*)(ws + VTOFF);
    bf16* Wtb = (bf16*)(ws + WTOFF);
    float* Op  = (float*)(ws + OPOFF);
    float* lp  = (float*)(ws + LPOFF);
    float* scr = (float*)(ws + SCROFF);

    cvtw_kernel<<<96, 256, 0, stream>>>(Wq, Wk, Wv, Wtb);
    proj_kernel<<<M_/64, 512, 0, stream>>>(x, Wtb, Qb, Kb, Vtb);
    attn_kernel<<<512, 256, 0, stream>>>(Qb, Kb, Vtb, outp, Op, lp);
    attn_ab<0><<<512, 256, 0, stream>>>(Qb, Kb, Vtb, scr);
    attn_ab<1><<<512, 256, 0, stream>>>(Qb, Kb, Vtb, scr);
    attn_ab<2><<<512, 256, 0, stream>>>(Qb, Kb, Vtb, scr);
    merge_kernel<<<2048, 256, 0, stream>>>(outp, Op, lp);
}

// Round 9
// 272.900 us; speedup vs baseline: 3.0624x; 3.0624x over previous
//
#include <hip/hip_runtime.h>
#include <hip/hip_bf16.h>
#include <math.h>

#define B_ 4
#define T_ 4096
#define D_ 2048
#define H_ 128
#define M_ (B_*T_)   // 16384 rows

typedef __bf16 bf16;
typedef __attribute__((ext_vector_type(8))) __bf16 bf16x8;
typedef __attribute__((ext_vector_type(4))) float f32x4;
typedef __attribute__((ext_vector_type(16))) float f32x16;

#define MFMA16(a,b,c) __builtin_amdgcn_mfma_f32_16x16x32_bf16(a,b,c,0,0,0)
#define MFMA32(a,b,c) __builtin_amdgcn_mfma_f32_32x32x16_bf16(a,b,c,0,0,0)

typedef __attribute__((address_space(3))) unsigned int lds_u32_t;
typedef const __attribute__((address_space(1))) unsigned int glb_u32_t;

__device__ __forceinline__ void cp16(void* lds, const void* g) {
    __builtin_amdgcn_global_load_lds((glb_u32_t*)g, (lds_u32_t*)lds, 16, 0, 0);
}

// ws layout (bytes)
#define QOFF   0u
#define KOFF   (4u<<20)
#define VTOFF  (8u<<20)
#define WTOFF  (12u<<20)            // 3 * 128 * 2048 bf16 = 1.5 MiB
#define OPOFF  (14u<<20)            // ks=1..3 partial O, fp32, 3 x 8 MiB
#define LPOFF  (OPOFF + 25165824u)  // l partials [4][16384] fp32

// ---------------------------------------------------------------------------
// W convert+transpose: W[2048][128] fp32 -> Wt[mat][128][2048] bf16.
// Wq pre-scaled by log2(e)/sqrt(H) so attention uses bare exp2.
// ---------------------------------------------------------------------------
__global__ __launch_bounds__(256) void cvtw_kernel(
    const float* __restrict__ Wq, const float* __restrict__ Wk,
    const float* __restrict__ Wv, bf16* __restrict__ Wtb)
{
    __shared__ __align__(16) bf16 U[128 * 72];   // [n][k], stride 72
    const int tid = threadIdx.x;
    const int m  = blockIdx.x >> 5;              // 0..2
    const int kt = blockIdx.x & 31;              // 0..31
    const int k0 = kt * 64;
    const float* W = (m == 0) ? Wq : ((m == 1) ? Wk : Wv);
    const float sc = (m == 0) ? 0.12753102105128444f : 1.0f;  // log2e/sqrt(128)

    #pragma unroll
    for (int u = 0; u < 8; u++) {
        int id = tid + u * 256;
        int kr = id >> 5, c4 = id & 31;
        float4 v = *(const float4*)(W + (size_t)(k0 + kr) * H_ + c4 * 4);
        U[(c4*4 + 0) * 72 + kr] = (bf16)(v.x * sc);
        U[(c4*4 + 1) * 72 + kr] = (bf16)(v.y * sc);
        U[(c4*4 + 2) * 72 + kr] = (bf16)(v.z * sc);
        U[(c4*4 + 3) * 72 + kr] = (bf16)(v.w * sc);
    }
    __syncthreads();
    #pragma unroll
    for (int u = 0; u < 4; u++) {
        int id = tid + u * 256;
        int n = id >> 3, kc = id & 7;
        bf16x8 v = *(const bf16x8*)((const char*)U + n * 144 + kc * 16);
        *(bf16x8*)((char*)Wtb + (size_t)m * 524288 + (size_t)n * 4096
                   + k0 * 2 + kc * 16) = v;
    }
}

// ---------------------------------------------------------------------------
// Fused QKV projection, 32x32x16 MFMA. Block 512 thr / 8 waves, M-tile 64.
// X loads are NONTEMPORAL (via clang ext_vector f32x4): X (134MB, read-once)
// was evicting the 1.5MB W tiles from per-XCD L2 (round-2 FETCH=287MB).
// ---------------------------------------------------------------------------
__global__ __launch_bounds__(512, 2) void proj_kernel(
    const float* __restrict__ X, const bf16* __restrict__ Wtb,
    bf16* __restrict__ Qb, bf16* __restrict__ Kb, bf16* __restrict__ Vtb)
{
    __shared__ __align__(16) char smem[114688];

    const int tid = threadIdx.x;
    const int w = tid >> 6, lane = tid & 63;
    const int c31 = lane & 31, kh = lane >> 5;
    const int mh = w >> 2;
    const int ng = w & 3;
    const int m0 = blockIdx.x * 64;

    f32x16 acc[3];
    #pragma unroll
    for (int t = 0; t < 3; t++)
        #pragma unroll
        for (int r = 0; r < 16; r++) acc[t][r] = 0.f;

    #pragma unroll
    for (int u = 0; u < 6; u++) {
        int s = tid + u * 512;
        int n = s >> 3, ccs = s & 7;
        int kc = ccs ^ (n & 7);
        int mat = n >> 7, ncol = n & 127;
        cp16(smem + 16384 + s * 16,
             (const char*)Wtb + (size_t)mat * 524288 + (size_t)ncol * 4096 + kc * 16);
    }
    {
        int r = tid >> 3, cc = tid & 7;
        const float* src = X + (size_t)(m0 + r) * D_ + cc * 8;
        f32x4 v0 = __builtin_nontemporal_load((const f32x4*)src);
        f32x4 v1 = __builtin_nontemporal_load((const f32x4*)(src + 4));
        union { bf16 h[8]; uint4 u4; } pk;
        pk.h[0]=(bf16)v0[0]; pk.h[1]=(bf16)v0[1]; pk.h[2]=(bf16)v0[2]; pk.h[3]=(bf16)v0[3];
        pk.h[4]=(bf16)v1[0]; pk.h[5]=(bf16)v1[1]; pk.h[6]=(bf16)v1[2]; pk.h[7]=(bf16)v1[3];
        *(uint4*)(smem + (r * 8 + (cc ^ (r & 7))) * 16) = pk.u4;
    }
    __syncthreads();

    for (int it = 0; it < 32; it++) {
        const int cur = it & 1;
        char* xcur = smem + cur * 8192;
        char* wcur = smem + 16384 + cur * 49152;
        f32x4 xv0, xv1;
        if (it < 31) {
            const int k1 = (it + 1) * 64;
            char* wnxt = smem + 16384 + (cur ^ 1) * 49152;
            #pragma unroll
            for (int u = 0; u < 6; u++) {
                int s = tid + u * 512;
                int n = s >> 3, ccs = s & 7;
                int kc = ccs ^ (n & 7);
                int mat = n >> 7, ncol = n & 127;
                cp16(wnxt + s * 16,
                     (const char*)Wtb + (size_t)mat * 524288 + (size_t)ncol * 4096
                     + k1 * 2 + kc * 16);
            }
            int r = tid >> 3, cc = tid & 7;
            const float* src = X + (size_t)(m0 + r) * D_ + k1 + cc * 8;
            xv0 = __builtin_nontemporal_load((const f32x4*)src);
            xv1 = __builtin_nontemporal_load((const f32x4*)(src + 4));
        }
        #pragma unroll
        for (int s = 0; s < 4; s++) {
            int c = s * 2 + kh;
            int rr = mh * 32 + c31;
            bf16x8 af = *(const bf16x8*)(xcur + (rr * 8 + (c ^ (rr & 7))) * 16);
            #pragma unroll
            for (int t = 0; t < 3; t++) {
                int n = ng * 96 + t * 32 + c31;
                bf16x8 bfr = *(const bf16x8*)(wcur + (n * 8 + (c ^ (n & 7))) * 16);
                acc[t] = MFMA32(af, bfr, acc[t]);
            }
        }
        if (it < 31) {
            char* xnxt = smem + (cur ^ 1) * 8192;
            int r = tid >> 3, cc = tid & 7;
            union { bf16 h[8]; uint4 u4; } pk;
            pk.h[0]=(bf16)xv0[0]; pk.h[1]=(bf16)xv0[1]; pk.h[2]=(bf16)xv0[2]; pk.h[3]=(bf16)xv0[3];
            pk.h[4]=(bf16)xv1[0]; pk.h[5]=(bf16)xv1[1]; pk.h[6]=(bf16)xv1[2]; pk.h[7]=(bf16)xv1[3];
            *(uint4*)(xnxt + (r * 8 + (cc ^ (r & 7))) * 16) = pk.u4;
        }
        __syncthreads();
    }

    #pragma unroll
    for (int t = 0; t < 3; t++) {
        int nb = ng * 96 + t * 32;
        if ((nb >> 7) == 2) {
            int ncol = (nb & 127) + c31;
            #pragma unroll
            for (int g = 0; g < 4; g++) {
                int m = m0 + mh * 32 + g * 8 + kh * 4;
                union { bf16 h[4]; uint2 u2; } pk;
                #pragma unroll
                for (int e = 0; e < 4; e++) pk.h[e] = (bf16)acc[t][g*4 + e];
                *(uint2*)((char*)Vtb + (size_t)ncol * 32768 + (size_t)m * 2) = pk.u2;
            }
        }
    }
    bf16* U = (bf16*)smem;
    #pragma unroll
    for (int mat = 0; mat < 2; mat++) {
        __syncthreads();
        #pragma unroll
        for (int t = 0; t < 3; t++) {
            int nb = ng * 96 + t * 32;
            if ((nb >> 7) == mat) {
                int lcol = (nb & 127) + c31;
                #pragma unroll
                for (int r = 0; r < 16; r++) {
                    int row = mh * 32 + (r & 3) + 8 * (r >> 2) + 4 * kh;
                    U[row * 136 + lcol] = (bf16)acc[t][r];
                }
            }
        }
        __syncthreads();
        bf16* og = (mat == 0) ? Qb : Kb;
        #pragma unroll
        for (int u = 0; u < 2; u++) {
            int id = tid + u * 512;
            int rr = id >> 4, cc = id & 15;
            bf16x8 v = *(const bf16x8*)((const char*)U + rr * 272 + cc * 16);
            *(bf16x8*)((char*)og + (size_t)(m0 + rr) * 256 + cc * 16) = v;
        }
    }
}

// ---------------------------------------------------------------------------
// Flash attention v6 = v4 structure + addressing-remat fix.
// 4 waves x 32 q-rows; KVBLK=32; K+V double-buffered in LDS; wave-private P
// (pitch 80B). All per-lane LDS offsets precomputed ONCE and pinned in VGPRs
// (asm "+v") so the compiler cannot rematerialize the swizzle math per iter
// (v4: VALUBusy 52% at VGPR=84 -> remat). Staging via two 64-bit cursors
// (+8192B / +64B per iter) and one XOR buffer toggle.
// ---------------------------------------------------------------------------
__global__ __launch_bounds__(256, 3) void attn_kernel(
    const bf16* __restrict__ Qb, const bf16* __restrict__ Kb,
    const bf16* __restrict__ Vtb,
    float* __restrict__ Out0, float* __restrict__ Opart,
    float* __restrict__ lpart)
{
    __shared__ __align__(16) char smem[43008];
    // K: 0/8192 | V: 16384/24576 | P: 32768 (4 waves x 32 rows x 80B)

    const int tid = threadIdx.x;
    const int w = tid >> 6, lane = tid & 63;
    const int c15 = lane & 15, quad = (lane >> 4) & 3;

    const int bx = blockIdx.x;
    const int ks = bx & 3;
    const int qt = bx >> 2;             // 0..127
    const int b = qt >> 5;
    const int row0 = b*T_ + (qt & 31)*128;
    const int kvrow = b*T_ + ks*1024;

    // Q B-frags
    bf16x8 qf[2][4];
    #pragma unroll
    for (int mg = 0; mg < 2; mg++) {
        const char* qrow = (const char*)Qb
            + (size_t)(row0 + w*32 + mg*16 + c15) * 256 + quad*16;
        #pragma unroll
        for (int kk = 0; kk < 4; kk++)
            qf[mg][kk] = *(const bf16x8*)(qrow + kk*64);
    }

    // ---- pinned loop-invariant per-lane byte offsets ----
    unsigned kfo[2][4];
    #pragma unroll
    for (int kq = 0; kq < 2; kq++)
        #pragma unroll
        for (int kk = 0; kk < 4; kk++) {
            int key = kq*16 + c15;
            int ck = kk*4 + quad;
            unsigned off = (unsigned)((key*16 + ((ck & 8) | ((ck ^ key) & 7)))*16);
            asm volatile("" : "+v"(off));
            kfo[kq][kk] = off;
        }
    unsigned pwb = (unsigned)(32768 + w*2560 + c15*80 + quad*8);   // P write base
    unsigned prb = (unsigned)(32768 + w*2560 + c15*80 + quad*16);  // P read base
    unsigned vfb = (unsigned)(16384 + c15*64
                              + ((quad ^ ((c15 >> 1) & 3)) & 3)*16); // V read base
    asm volatile("" : "+v"(pwb), "+v"(prb), "+v"(vfb));

    // ---- staging: prologue tile 0 + cursors for tiles 1..31 ----
    const int r_ = tid >> 4, csw_ = tid & 15;
    const int cg_ = (csw_ & 8) | ((csw_ ^ r_) & 7);
    const int h_ = tid >> 2, f_ = tid & 3;
    const int cv_ = (f_ ^ ((h_ >> 1) & 3)) & 3;

    cp16(smem + tid*16,
         (const char*)Kb + (size_t)(kvrow + r_)*256 + cg_*16);
    cp16(smem + (tid + 256)*16,
         (const char*)Kb + (size_t)(kvrow + 16 + r_)*256 + cg_*16);
    cp16(smem + 16384 + tid*16,
         (const char*)Vtb + (size_t)h_*32768 + (size_t)(kvrow + cv_*8)*2);
    cp16(smem + 16384 + (tid + 256)*16,
         (const char*)Vtb + (size_t)(64 + h_)*32768 + (size_t)(kvrow + cv_*8)*2);

    const char* kg = (const char*)Kb + (size_t)(kvrow + 32 + r_)*256 + cg_*16;
    const char* vg = (const char*)Vtb + (size_t)h_*32768
                     + (size_t)(kvrow + 32 + cv_*8)*2;

    f32x4 o[2][8];
    #pragma unroll
    for (int mg = 0; mg < 2; mg++)
        #pragma unroll
        for (int ng = 0; ng < 8; ng++)
            #pragma unroll
            for (int r = 0; r < 4; r++) o[mg][ng][r] = 0.f;
    float lsum[2] = {0.f, 0.f};

    __syncthreads();

    int ko = 0;   // current K-buf byte offset (0/8192); V shares the toggle
    for (int it = 0; it < 32; it++) {
        if (it < 31) {
            int dst = ko ^ 8192;
            cp16(smem + dst + tid*16, kg);
            cp16(smem + dst + 4096 + tid*16, kg + 4096);
            cp16(smem + 16384 + dst + tid*16, vg);
            cp16(smem + 16384 + dst + 4096 + tid*16, vg + 2097152);
            kg += 8192;   // 32 rows * 256B
            vg += 64;     // 32 keys * 2B
        }

        // S: D[key][m] via MFMA16(A=K, B=Q); K-frags shared by both m-groups.
        #pragma unroll
        for (int kq = 0; kq < 2; kq++) {
            bf16x8 kf[4];
            #pragma unroll
            for (int kk = 0; kk < 4; kk++)
                kf[kk] = *(const bf16x8*)(smem + ko + kfo[kq][kk]);
            #pragma unroll
            for (int mg = 0; mg < 2; mg++) {
                f32x4 sc = (f32x4){0.f,0.f,0.f,0.f};
                __builtin_amdgcn_s_setprio(1);
                #pragma unroll
                for (int kk = 0; kk < 4; kk++)
                    sc = MFMA16(kf[kk], qf[mg][kk], sc);
                __builtin_amdgcn_s_setprio(0);
                union { bf16 h[4]; uint2 u2; } pk;
                #pragma unroll
                for (int r = 0; r < 4; r++) {
                    float p = exp2f(sc[r]);
                    lsum[mg] += p;
                    pk.h[r] = (bf16)p;
                }
                *(uint2*)(smem + pwb + mg*1280 + kq*32) = pk.u2;
            }
        }

        // PV: o[mg][ng] += P(16x32) * V(32x16); V-frags shared across mg.
        bf16x8 pf0 = *(const bf16x8*)(smem + prb);
        bf16x8 pf1 = *(const bf16x8*)(smem + prb + 1280);
        __builtin_amdgcn_s_setprio(1);
        #pragma unroll
        for (int ng = 0; ng < 8; ng++) {
            bf16x8 vf = *(const bf16x8*)(smem + ko + vfb + ng*1024);
            o[0][ng] = MFMA16(pf0, vf, o[0][ng]);
            o[1][ng] = MFMA16(pf1, vf, o[1][ng]);
        }
        __builtin_amdgcn_s_setprio(0);

        __syncthreads();   // all reads of bufs[ko] done; prefetch visible
        ko ^= 8192;
    }

    __syncthreads();       // P region dead everywhere -> reuse as lred
    float* lred = (float*)(smem + 32768);
    #pragma unroll
    for (int mg = 0; mg < 2; mg++) {
        float v = lsum[mg];
        v += __shfl_xor(v, 16);
        v += __shfl_xor(v, 32);
        if (lane < 16) lred[w*32 + mg*16 + c15] = v;
    }
    __syncthreads();
    if (tid < 128)
        lpart[ks*M_ + row0 + tid] = lred[tid];

    float* Od = (ks == 0) ? Out0 : (Opart + (size_t)(ks - 1) * M_ * H_);
    #pragma unroll
    for (int mg = 0; mg < 2; mg++)
        #pragma unroll
        for (int ng = 0; ng < 8; ng++)
            #pragma unroll
            for (int r = 0; r < 4; r++)
                Od[(size_t)(row0 + w*32 + mg*16 + quad*4 + r)*H_ + ng*16 + c15]
                    = o[mg][ng][r];
}

// ---------------------------------------------------------------------------
// Merge: out = (O0 + O1 + O2 + O3) / (l0 + l1 + l2 + l3). NT loads on the
// read-once partials (clang ext_vector f32x4).
// ---------------------------------------------------------------------------
__global__ __launch_bounds__(256) void merge_kernel(
    float* __restrict__ Out, const float* __restrict__ Opart,
    const float* __restrict__ lp)
{
    int id = blockIdx.x * 256 + threadIdx.x;   // 524288 float4 groups
    int row = id >> 5;
    float inv = 1.0f / (lp[row] + lp[M_ + row] + lp[2*M_ + row] + lp[3*M_ + row]);
    f32x4 a  = __builtin_nontemporal_load((const f32x4*)(Out + (size_t)id*4));
    f32x4 b1 = __builtin_nontemporal_load((const f32x4*)(Opart + (size_t)id*4));
    f32x4 b2 = __builtin_nontemporal_load((const f32x4*)(Opart + (size_t)M_*H_ + (size_t)id*4));
    f32x4 b3 = __builtin_nontemporal_load((const f32x4*)(Opart + (size_t)2*M_*H_ + (size_t)id*4));
    f32x4 rr;
    rr[0] = (a[0] + b1[0] + b2[0] + b3[0]) * inv;
    rr[1] = (a[1] + b1[1] + b2[1] + b3[1]) * inv;
    rr[2] = (a[2] + b1[2] + b2[2] + b3[2]) * inv;
    rr[3] = (a[3] + b1[3] + b2[3] + b3[3]) * inv;
    *(f32x4*)(Out + (size_t)id*4) = rr;
}

extern "C" void kernel_launch(void* const* d_in, const int* in_sizes, int n_in,
                              void* d_out, int out_size, void* d_ws, size_t ws_size,
                              hipStream_t stream) {
    const float* x  = (const float*)d_in[0];
    const float* Wq = (const float*)d_in[1];
    const float* Wk = (const float*)d_in[2];
    const float* Wv = (const float*)d_in[3];
    float* outp = (float*)d_out;
    char* ws = (char*)d_ws;

    bf16* Qb  = (bf16*)(ws + QOFF);
    bf16* Kb  = (bf16*)(ws + KOFF);
    bf16* Vtb = (bf16*)(ws + VTOFF);
    bf16* Wtb = (bf16*)(ws + WTOFF);
    float* Op  = (float*)(ws + OPOFF);
    float* lp  = (float*)(ws + LPOFF);

    cvtw_kernel<<<96, 256, 0, stream>>>(Wq, Wk, Wv, Wtb);
    proj_kernel<<<M_/64, 512, 0, stream>>>(x, Wtb, Qb, Kb, Vtb);
    attn_kernel<<<512, 256, 0, stream>>>(Qb, Kb, Vtb, outp, Op, lp);
    merge_kernel<<<2048, 256, 0, stream>>>(outp, Op, lp);
}